// Round 1
// baseline (320.713 us; speedup 1.0000x reference)
//
#include <hip/hip_runtime.h>
#include <hip/hip_bf16.h>

// GraphSAGE layer: CSR build (int atomics) -> per-node mean aggregate ->
// fused linear(concat) + L2-normalize + relu + graph-norm + residual.
// c (mean-aggregated neighbors) is staged in d_out itself to minimize ws use.

#define TPB 256

__global__ void k_deg(const int* __restrict__ dst, int* __restrict__ deg, int E) {
    int e = blockIdx.x * TPB + threadIdx.x;
    if (e < E) atomicAdd(&deg[dst[e]], 1);
}

__global__ void k_bsum(const int* __restrict__ deg, int* __restrict__ bsum, int N) {
    __shared__ int sdata[4];
    int i = blockIdx.x * TPB + threadIdx.x;
    int v = (i < N) ? deg[i] : 0;
    for (int o = 32; o; o >>= 1) v += __shfl_xor(v, o);
    int lane = threadIdx.x & 63, w = threadIdx.x >> 6;
    if (lane == 0) sdata[w] = v;
    __syncthreads();
    if (threadIdx.x == 0) bsum[blockIdx.x] = sdata[0] + sdata[1] + sdata[2] + sdata[3];
}

// single-block exclusive scan of block sums (NB can exceed 256; loops in chunks)
__global__ void k_scanb(const int* __restrict__ bsum, int* __restrict__ boff, int NB,
                        int* __restrict__ offs_end, int E) {
    __shared__ int wsum[4];
    __shared__ int carry;
    if (threadIdx.x == 0) carry = 0;
    __syncthreads();
    for (int base = 0; base < NB; base += TPB) {
        int t = base + threadIdx.x;
        int v = (t < NB) ? bsum[t] : 0;
        int lane = threadIdx.x & 63, w = threadIdx.x >> 6;
        int x = v;
        for (int o = 1; o < 64; o <<= 1) { int y = __shfl_up(x, o); if (lane >= o) x += y; }
        if (lane == 63) wsum[w] = x;
        __syncthreads();
        int add = carry;
        for (int k = 0; k < w; ++k) add += wsum[k];
        if (t < NB) boff[t] = add + x - v;   // exclusive
        __syncthreads();
        if (threadIdx.x == 0) carry += wsum[0] + wsum[1] + wsum[2] + wsum[3];
        __syncthreads();
    }
    if (threadIdx.x == 0) *offs_end = E;
}

__global__ void k_offs(const int* __restrict__ deg, const int* __restrict__ boff,
                       int* __restrict__ offs, int* __restrict__ cursor, int N) {
    __shared__ int wsum[4];
    int i = blockIdx.x * TPB + threadIdx.x;
    int v = (i < N) ? deg[i] : 0;
    int lane = threadIdx.x & 63, w = threadIdx.x >> 6;
    int x = v;
    for (int o = 1; o < 64; o <<= 1) { int y = __shfl_up(x, o); if (lane >= o) x += y; }
    if (lane == 63) wsum[w] = x;
    __syncthreads();
    int add = boff[blockIdx.x];
    for (int k = 0; k < w; ++k) add += wsum[k];
    if (i < N) { int ex = add + x - v; offs[i] = ex; cursor[i] = ex; }
}

__global__ void k_scatter(const int* __restrict__ src, const int* __restrict__ dst,
                          int* __restrict__ cursor, int* __restrict__ esrc, int E) {
    int e = blockIdx.x * TPB + threadIdx.x;
    if (e < E) {
        int d = dst[e];
        int pos = atomicAdd(&cursor[d], 1);
        esrc[pos] = src[e];
    }
}

// one wave per node: mean of h[src] rows, float2 per lane (D=128)
__global__ void k_agg(const float* __restrict__ h, const int* __restrict__ offs,
                      const int* __restrict__ esrc, float* c, int N) {
    int wid = (blockIdx.x * TPB + threadIdx.x) >> 6;
    int lane = threadIdx.x & 63;
    if (wid >= N) return;
    int beg = offs[wid], end = offs[wid + 1];
    const float2* h2 = (const float2*)h;
    float ax = 0.f, ay = 0.f;
    for (int e = beg; e < end; ++e) {
        int s = esrc[e];
        float2 v = h2[s * 64 + lane];
        ax += v.x; ay += v.y;
    }
    float inv = 1.0f / fmaxf((float)(end - beg), 1.0f);
    float2 r; r.x = ax * inv; r.y = ay * inv;
    ((float2*)c)[wid * 64 + lane] = r;
}

// Fused NodeApply. W staged in LDS as bf16, 16B-granule XOR swizzle (g ^= j&7)
// for conflict-free ds_read_b128. 256 threads: j = tid&127 (output), p = tid>>7
// selects 2-node group; each thread accumulates 2 nodes per W read.
__launch_bounds__(TPB)
__global__ void k_apply(const float* __restrict__ h, const float* c,
                        const float* __restrict__ W, const float* __restrict__ b,
                        const float* __restrict__ snorm, float* out, int N) {
    extern __shared__ char smem[];
    unsigned short* Ws = (unsigned short*)smem;                     // [128][256] bf16, 64KB
    float (*in_s)[256] = (float(*)[256])(smem + 65536);             // [4][256] f32, 4KB
    float* red = (float*)(smem + 65536 + 4096);                     // [8]

    // stage W -> bf16 swizzled
    for (int idx = threadIdx.x; idx < 128 * 256; idx += TPB) {
        int j = idx >> 8, k = idx & 255;
        __hip_bfloat16 bv = __float2bfloat16(W[idx]);
        int g = k >> 3, t = k & 7;
        int gp = g ^ (j & 7);
        Ws[(j << 8) + (gp << 3) + t] = *(unsigned short*)&bv;
    }

    int j = threadIdx.x & 127;
    int p = threadIdx.x >> 7;
    int w = threadIdx.x >> 6;
    int lane = threadIdx.x & 63;
    int jm = j & 7;
    int q0 = 2 * p, q1 = 2 * p + 1;
    float bj = b[j];

    for (int nb = blockIdx.x * 4; nb < N; nb += gridDim.x * 4) {
        __syncthreads();  // protect in_s/red from previous iteration readers
        // stage inputs: in_s[q][k] = k<128 ? h[n_q][k] : c[n_q][k-128]
        for (int idx = threadIdx.x; idx < 4 * 256; idx += TPB) {
            int q = idx >> 8, k = idx & 255;
            int n = nb + q;
            float v = 0.f;
            if (n < N) v = (k < 128) ? h[n * 128 + k] : c[n * 128 + (k - 128)];
            in_s[q][k] = v;
        }
        __syncthreads();

        float a0 = bj, a1 = bj;
        #pragma unroll
        for (int g = 0; g < 32; ++g) {
            int gp = (g ^ jm) << 3;
            uint4 wv = *(const uint4*)(Ws + (j << 8) + gp);
            float w0 = __uint_as_float(wv.x << 16);
            float w1 = __uint_as_float(wv.x & 0xffff0000u);
            float w2 = __uint_as_float(wv.y << 16);
            float w3 = __uint_as_float(wv.y & 0xffff0000u);
            float w4 = __uint_as_float(wv.z << 16);
            float w5 = __uint_as_float(wv.z & 0xffff0000u);
            float w6 = __uint_as_float(wv.w << 16);
            float w7 = __uint_as_float(wv.w & 0xffff0000u);
            const float4* x0 = (const float4*)&in_s[q0][g << 3];
            const float4* x1 = (const float4*)&in_s[q1][g << 3];
            float4 p0 = x0[0], p1 = x0[1];
            float4 r0 = x1[0], r1 = x1[1];
            a0 += w0 * p0.x + w1 * p0.y + w2 * p0.z + w3 * p0.w
                + w4 * p1.x + w5 * p1.y + w6 * p1.z + w7 * p1.w;
            a1 += w0 * r0.x + w1 * r0.y + w2 * r0.z + w3 * r0.w
                + w4 * r1.x + w5 * r1.y + w6 * r1.z + w7 * r1.w;
        }

        // row L2 norm: reduce a^2 over j=0..127 (2 waves per node)
        float s0 = a0 * a0, s1 = a1 * a1;
        for (int o = 32; o; o >>= 1) { s0 += __shfl_xor(s0, o); s1 += __shfl_xor(s1, o); }
        if (lane == 0) {
            red[q0 * 2 + (w & 1)] = s0;
            red[q1 * 2 + (w & 1)] = s1;
        }
        __syncthreads();
        float n0 = red[q0 * 2] + red[q0 * 2 + 1];
        float n1 = red[q1 * 2] + red[q1 * 2 + 1];
        float inv0 = 1.0f / fmaxf(sqrtf(n0), 1e-12f);
        float inv1 = 1.0f / fmaxf(sqrtf(n1), 1e-12f);

        int nn0 = nb + q0, nn1 = nb + q1;
        if (nn0 < N)
            out[nn0 * 128 + j] = fmaxf(a0 * inv0, 0.f) * snorm[nn0] + in_s[q0][j];
        if (nn1 < N)
            out[nn1 * 128 + j] = fmaxf(a1 * inv1, 0.f) * snorm[nn1] + in_s[q1][j];
    }
}

extern "C" void kernel_launch(void* const* d_in, const int* in_sizes, int n_in,
                              void* d_out, int out_size, void* d_ws, size_t ws_size,
                              hipStream_t stream) {
    const float* h     = (const float*)d_in[0];
    const float* snorm = (const float*)d_in[1];
    const float* W     = (const float*)d_in[2];
    const float* b     = (const float*)d_in[3];
    const int*   src   = (const int*)d_in[4];
    const int*   dst   = (const int*)d_in[5];
    int N = in_sizes[1];            // snorm_n is [N,1]
    int E = in_sizes[4];
    float* out = (float*)d_out;

    char* ws = (char*)d_ws;
    size_t off = 0;
    auto alloc = [&](size_t bytes) {
        void* ptr = ws + off;
        off = (off + bytes + 255) & ~(size_t)255;
        return ptr;
    };
    int NB = (N + TPB - 1) / TPB;
    int* deg    = (int*)alloc((size_t)N * 4);
    int* offs   = (int*)alloc((size_t)(N + 1) * 4);
    int* cursor = (int*)alloc((size_t)N * 4);
    int* bsum   = (int*)alloc((size_t)NB * 4);
    int* boff   = (int*)alloc((size_t)NB * 4);
    int* esrc   = (int*)alloc((size_t)E * 4);

    hipMemsetAsync(deg, 0, (size_t)N * 4, stream);
    k_deg<<<(E + TPB - 1) / TPB, TPB, 0, stream>>>(dst, deg, E);
    k_bsum<<<NB, TPB, 0, stream>>>(deg, bsum, N);
    k_scanb<<<1, TPB, 0, stream>>>(bsum, boff, NB, offs + N, E);
    k_offs<<<NB, TPB, 0, stream>>>(deg, boff, offs, cursor, N);
    k_scatter<<<(E + TPB - 1) / TPB, TPB, 0, stream>>>(src, dst, cursor, esrc, E);

    float* c = out;  // reuse output buffer as scratch for aggregated means
    k_agg<<<(N * 64 + TPB - 1) / TPB, TPB, 0, stream>>>(h, offs, esrc, c, N);

    size_t smem = 65536 + 4096 + 64;
    k_apply<<<512, TPB, smem, stream>>>(h, c, W, b, snorm, out, N);
}

// Round 2
// 192.756 us; speedup vs baseline: 1.6638x; 1.6638x over previous
//
#include <hip/hip_runtime.h>
#include <hip/hip_bf16.h>

#define TPB 256

typedef __attribute__((ext_vector_type(8))) short bf16x8;
typedef __attribute__((ext_vector_type(4))) float f32x4;

__device__ inline unsigned short f2bf(float f) {
    unsigned u = __float_as_uint(f);
    unsigned r = u + 0x7fffu + ((u >> 16) & 1u);
    return (unsigned short)(r >> 16);
}
__device__ inline float bf2f(unsigned short s) {
    return __uint_as_float(((unsigned)s) << 16);
}

// ---- h -> (h_hi bf16 in ws, h_lo bf16 interleaved in d_out), W -> bf16 in ws
__global__ void k_cvt(const float* __restrict__ h, const float* __restrict__ W,
                      unsigned short* __restrict__ h_hi, char* __restrict__ outb,
                      unsigned short* __restrict__ Wb, int N) {
    int t = blockIdx.x * TPB + threadIdx.x;
    int nh4 = N * 32;                       // N*128/4 float4 groups
    if (t < nh4) {
        float4 v = ((const float4*)h)[t];
        ushort4 hi, lo;
        hi.x = f2bf(v.x); lo.x = f2bf(v.x - bf2f(hi.x));
        hi.y = f2bf(v.y); lo.y = f2bf(v.y - bf2f(hi.y));
        hi.z = f2bf(v.z); lo.z = f2bf(v.z - bf2f(hi.z));
        hi.w = f2bf(v.w); lo.w = f2bf(v.w - bf2f(hi.w));
        ((ushort4*)h_hi)[t] = hi;
        int row = t >> 5;                   // (t*4)/128
        int k   = (t & 31) << 2;            // (t*4)%128
        *(ushort4*)(outb + (size_t)row * 512 + 256 + (size_t)k * 2) = lo;
    } else {
        int w4 = t - nh4;
        if (w4 < 8192) {                    // 128*256/4
            float4 v = ((const float4*)W)[w4];
            ushort4 hi;
            hi.x = f2bf(v.x); hi.y = f2bf(v.y);
            hi.z = f2bf(v.z); hi.w = f2bf(v.w);
            ((ushort4*)Wb)[w4] = hi;
        }
    }
}

// ---- CSR build ----
__global__ void k_deg(const int* __restrict__ dst, int* __restrict__ deg, int E) {
    int e = blockIdx.x * TPB + threadIdx.x;
    if (e < E) atomicAdd(&deg[dst[e]], 1);
}

__global__ void k_bsum(const int* __restrict__ deg, int* __restrict__ bsum, int N) {
    __shared__ int sdata[4];
    int i = blockIdx.x * TPB + threadIdx.x;
    int v = (i < N) ? deg[i] : 0;
    for (int o = 32; o; o >>= 1) v += __shfl_xor(v, o);
    int lane = threadIdx.x & 63, w = threadIdx.x >> 6;
    if (lane == 0) sdata[w] = v;
    __syncthreads();
    if (threadIdx.x == 0) bsum[blockIdx.x] = sdata[0] + sdata[1] + sdata[2] + sdata[3];
}

__global__ void k_scanb(const int* __restrict__ bsum, int* __restrict__ boff, int NB,
                        int* __restrict__ offs_end, int E) {
    __shared__ int wsum[4];
    __shared__ int carry;
    if (threadIdx.x == 0) carry = 0;
    __syncthreads();
    for (int base = 0; base < NB; base += TPB) {
        int t = base + threadIdx.x;
        int v = (t < NB) ? bsum[t] : 0;
        int lane = threadIdx.x & 63, w = threadIdx.x >> 6;
        int x = v;
        for (int o = 1; o < 64; o <<= 1) { int y = __shfl_up(x, o); if (lane >= o) x += y; }
        if (lane == 63) wsum[w] = x;
        __syncthreads();
        int add = carry;
        for (int k = 0; k < w; ++k) add += wsum[k];
        if (t < NB) boff[t] = add + x - v;   // exclusive
        __syncthreads();
        if (threadIdx.x == 0) carry += wsum[0] + wsum[1] + wsum[2] + wsum[3];
        __syncthreads();
    }
    if (threadIdx.x == 0) *offs_end = E;
}

__global__ void k_offs(const int* __restrict__ deg, const int* __restrict__ boff,
                       int* __restrict__ offs, int* __restrict__ cursor, int N) {
    __shared__ int wsum[4];
    int i = blockIdx.x * TPB + threadIdx.x;
    int v = (i < N) ? deg[i] : 0;
    int lane = threadIdx.x & 63, w = threadIdx.x >> 6;
    int x = v;
    for (int o = 1; o < 64; o <<= 1) { int y = __shfl_up(x, o); if (lane >= o) x += y; }
    if (lane == 63) wsum[w] = x;
    __syncthreads();
    int add = boff[blockIdx.x];
    for (int k = 0; k < w; ++k) add += wsum[k];
    if (i < N) { int ex = add + x - v; offs[i] = ex; cursor[i] = ex; }
}

__global__ void k_scatter(const int* __restrict__ src, const int* __restrict__ dst,
                          int* __restrict__ cursor, int* __restrict__ esrc, int E) {
    int e = blockIdx.x * TPB + threadIdx.x;
    if (e < E) {
        int d = dst[e];
        int pos = atomicAdd(&cursor[d], 1);
        esrc[pos] = src[e];
    }
}

// ---- mean aggregate over bf16 h_hi; write c (bf16) interleaved into d_out ----
__global__ void k_agg(const unsigned short* __restrict__ h_hi, const int* __restrict__ offs,
                      const int* __restrict__ esrc, char* __restrict__ outb, int N) {
    int wid = (blockIdx.x * TPB + threadIdx.x) >> 6;
    int lane = threadIdx.x & 63;
    if (wid >= N) return;
    int beg = offs[wid], end = offs[wid + 1];
    const unsigned* h2 = (const unsigned*)h_hi;
    float ax = 0.f, ay = 0.f;
    int e = beg;
    for (; e + 1 < end; e += 2) {
        int s0 = esrc[e], s1 = esrc[e + 1];
        unsigned u0 = h2[(size_t)s0 * 64 + lane];
        unsigned u1 = h2[(size_t)s1 * 64 + lane];
        ax += __uint_as_float(u0 << 16) + __uint_as_float(u1 << 16);
        ay += __uint_as_float(u0 & 0xffff0000u) + __uint_as_float(u1 & 0xffff0000u);
    }
    if (e < end) {
        unsigned u0 = h2[(size_t)esrc[e] * 64 + lane];
        ax += __uint_as_float(u0 << 16);
        ay += __uint_as_float(u0 & 0xffff0000u);
    }
    float inv = 1.0f / fmaxf((float)(end - beg), 1.0f);
    unsigned pk = ((unsigned)f2bf(ay * inv) << 16) | (unsigned)f2bf(ax * inv);
    *(unsigned*)(outb + (size_t)wid * 512 + (size_t)lane * 4) = pk;
}

// ---- MFMA NodeApply: per wave 64 rows x 128 cols; A/B frags direct from cache ----
__launch_bounds__(TPB)
__global__ void k_apply(const unsigned short* __restrict__ h_hi,
                        const char* __restrict__ cl,        // d_out bytes: c + h_lo interleaved
                        const unsigned short* __restrict__ Wb,
                        const float* __restrict__ h,
                        const float* __restrict__ bia,
                        const float* __restrict__ snorm,
                        float* __restrict__ out, int N) {
    int lane = threadIdx.x & 63;
    int l15 = lane & 15, l4 = lane >> 4;
    int wave = threadIdx.x >> 6;
    int r0 = blockIdx.x * 256 + wave * 64;

    f32x4 acc[4][8] = {};

    #pragma unroll 2
    for (int kc = 0; kc < 8; ++kc) {
        bf16x8 Bf[8];
        #pragma unroll
        for (int n = 0; n < 8; ++n) {
            Bf[n] = *(const bf16x8*)((const char*)Wb +
                     ((size_t)(n * 16 + l15) * 512 + (size_t)kc * 64 + (size_t)l4 * 16));
        }
        #pragma unroll
        for (int rf = 0; rf < 4; ++rf) {
            int row = r0 + rf * 16 + l15;
            if (row > N - 1) row = N - 1;
            if (kc < 4) {
                bf16x8 ah = *(const bf16x8*)((const char*)h_hi +
                             ((size_t)row * 256 + (size_t)kc * 64 + (size_t)l4 * 16));
                bf16x8 al = *(const bf16x8*)(cl +
                             ((size_t)row * 512 + 256 + (size_t)kc * 64 + (size_t)l4 * 16));
                #pragma unroll
                for (int n = 0; n < 8; ++n) {
                    acc[rf][n] = __builtin_amdgcn_mfma_f32_16x16x32_bf16(ah, Bf[n], acc[rf][n], 0, 0, 0);
                    acc[rf][n] = __builtin_amdgcn_mfma_f32_16x16x32_bf16(al, Bf[n], acc[rf][n], 0, 0, 0);
                }
            } else {
                bf16x8 ac = *(const bf16x8*)(cl +
                             ((size_t)row * 512 + (size_t)(kc - 4) * 64 + (size_t)l4 * 16));
                #pragma unroll
                for (int n = 0; n < 8; ++n)
                    acc[rf][n] = __builtin_amdgcn_mfma_f32_16x16x32_bf16(ac, Bf[n], acc[rf][n], 0, 0, 0);
            }
        }
    }

    float bn[8];
    #pragma unroll
    for (int n = 0; n < 8; ++n) bn[n] = bia[n * 16 + l15];

    #pragma unroll
    for (int rf = 0; rf < 4; ++rf) {
        float sq[4] = {0.f, 0.f, 0.f, 0.f};
        #pragma unroll
        for (int n = 0; n < 8; ++n) {
            #pragma unroll
            for (int g = 0; g < 4; ++g) {
                acc[rf][n][g] += bn[n];
                sq[g] += acc[rf][n][g] * acc[rf][n][g];
            }
        }
        #pragma unroll
        for (int g = 0; g < 4; ++g) {
            sq[g] += __shfl_xor(sq[g], 1);
            sq[g] += __shfl_xor(sq[g], 2);
            sq[g] += __shfl_xor(sq[g], 4);
            sq[g] += __shfl_xor(sq[g], 8);
        }
        #pragma unroll
        for (int g = 0; g < 4; ++g) {
            int row = r0 + rf * 16 + l4 * 4 + g;
            if (row < N) {
                float invn = 1.0f / fmaxf(sqrtf(sq[g]), 1e-12f);
                float sn = snorm[row];
                #pragma unroll
                for (int n = 0; n < 8; ++n) {
                    int col = n * 16 + l15;
                    float v = fmaxf(acc[rf][n][g] * invn, 0.f) * sn + h[(size_t)row * 128 + col];
                    out[(size_t)row * 128 + col] = v;
                }
            }
        }
    }
}

extern "C" void kernel_launch(void* const* d_in, const int* in_sizes, int n_in,
                              void* d_out, int out_size, void* d_ws, size_t ws_size,
                              hipStream_t stream) {
    const float* h     = (const float*)d_in[0];
    const float* snorm = (const float*)d_in[1];
    const float* W     = (const float*)d_in[2];
    const float* b     = (const float*)d_in[3];
    const int*   src   = (const int*)d_in[4];
    const int*   dst   = (const int*)d_in[5];
    int N = in_sizes[1];
    int E = in_sizes[4];
    float* out = (float*)d_out;
    char* outb = (char*)d_out;

    char* ws = (char*)d_ws;
    size_t off = 0;
    auto alloc = [&](size_t bytes) {
        void* ptr = ws + off;
        off = (off + bytes + 255) & ~(size_t)255;
        return ptr;
    };
    int NB = (N + TPB - 1) / TPB;
    int* deg    = (int*)alloc((size_t)N * 4);
    int* offs   = (int*)alloc((size_t)(N + 1) * 4);
    int* cursor = (int*)alloc((size_t)N * 4);
    int* bsum   = (int*)alloc((size_t)NB * 4);
    int* boff   = (int*)alloc((size_t)NB * 4);
    int* esrc   = (int*)alloc((size_t)E * 4);
    unsigned short* h_hi = (unsigned short*)alloc((size_t)N * 128 * 2);
    unsigned short* Wb   = (unsigned short*)alloc((size_t)128 * 256 * 2);

    hipMemsetAsync(deg, 0, (size_t)N * 4, stream);

    int cvt_items = N * 32 + 8192;                      // h float4 groups + W float4 groups
    k_cvt<<<(cvt_items + TPB - 1) / TPB, TPB, 0, stream>>>(h, W, h_hi, outb, Wb, N);

    k_deg<<<(E + TPB - 1) / TPB, TPB, 0, stream>>>(dst, deg, E);
    k_bsum<<<NB, TPB, 0, stream>>>(deg, bsum, N);
    k_scanb<<<1, TPB, 0, stream>>>(bsum, boff, NB, offs + N, E);
    k_offs<<<NB, TPB, 0, stream>>>(deg, boff, offs, cursor, N);
    k_scatter<<<(E + TPB - 1) / TPB, TPB, 0, stream>>>(src, dst, cursor, esrc, E);

    k_agg<<<((size_t)N * 64 + TPB - 1) / TPB, TPB, 0, stream>>>(h_hi, offs, esrc, outb, N);

    int nblk = (N + 255) / 256;
    k_apply<<<nblk, TPB, 0, stream>>>(h_hi, outb, Wb, h, b, snorm, out, N);
}

// Round 3
// 137.596 us; speedup vs baseline: 2.3308x; 1.4009x over previous
//
#include <hip/hip_runtime.h>
#include <hip/hip_bf16.h>

#define TPB 256

typedef __attribute__((ext_vector_type(8))) short bf16x8;
typedef __attribute__((ext_vector_type(4))) float f32x4;

__device__ inline unsigned short f2bf(float f) {
    unsigned u = __float_as_uint(f);
    unsigned r = u + 0x7fffu + ((u >> 16) & 1u);
    return (unsigned short)(r >> 16);
}
__device__ inline float bf2f(unsigned short s) {
    return __uint_as_float(((unsigned)s) << 16);
}

// ---- fused: h -> (h_hi bf16 ws, h_lo bf16 in d_out), W -> bf16, edge rank ----
__global__ void k_prep(const float* __restrict__ h, const float* __restrict__ W,
                       const int* __restrict__ dst,
                       unsigned short* __restrict__ h_hi, char* __restrict__ outb,
                       unsigned short* __restrict__ Wb,
                       int* __restrict__ deg, unsigned short* __restrict__ rank,
                       int N, int E) {
    int t = blockIdx.x * TPB + threadIdx.x;
    int nh4 = N * 32;                       // N*128/4 float4 groups
    if (t < nh4) {
        float4 v = ((const float4*)h)[t];
        ushort4 hi, lo;
        hi.x = f2bf(v.x); lo.x = f2bf(v.x - bf2f(hi.x));
        hi.y = f2bf(v.y); lo.y = f2bf(v.y - bf2f(hi.y));
        hi.z = f2bf(v.z); lo.z = f2bf(v.z - bf2f(hi.z));
        hi.w = f2bf(v.w); lo.w = f2bf(v.w - bf2f(hi.w));
        ((ushort4*)h_hi)[t] = hi;
        int row = t >> 5;
        int k   = (t & 31) << 2;
        *(ushort4*)(outb + (size_t)row * 512 + 256 + (size_t)k * 2) = lo;
    } else if (t - nh4 < 8192) {            // 128*256/4 W groups
        int w4 = t - nh4;
        float4 v = ((const float4*)W)[w4];
        ushort4 hi;
        hi.x = f2bf(v.x); hi.y = f2bf(v.y);
        hi.z = f2bf(v.z); hi.w = f2bf(v.w);
        ((ushort4*)Wb)[w4] = hi;
    }
    if (t < E) {
        int d = dst[t];
        int r = atomicAdd(&deg[d], 1);
        rank[t] = (unsigned short)r;
    }
}

// ---- scan over deg -> offs ----
__global__ void k_bsum(const int* __restrict__ deg, int* __restrict__ bsum, int N) {
    __shared__ int sdata[4];
    int i = blockIdx.x * TPB + threadIdx.x;
    int v = (i < N) ? deg[i] : 0;
    for (int o = 32; o; o >>= 1) v += __shfl_xor(v, o);
    int lane = threadIdx.x & 63, w = threadIdx.x >> 6;
    if (lane == 0) sdata[w] = v;
    __syncthreads();
    if (threadIdx.x == 0) bsum[blockIdx.x] = sdata[0] + sdata[1] + sdata[2] + sdata[3];
}

__global__ void k_scanb(const int* __restrict__ bsum, int* __restrict__ boff, int NB,
                        int* __restrict__ offs_end, int E) {
    __shared__ int wsum[4];
    __shared__ int carry;
    if (threadIdx.x == 0) carry = 0;
    __syncthreads();
    for (int base = 0; base < NB; base += TPB) {
        int t = base + threadIdx.x;
        int v = (t < NB) ? bsum[t] : 0;
        int lane = threadIdx.x & 63, w = threadIdx.x >> 6;
        int x = v;
        for (int o = 1; o < 64; o <<= 1) { int y = __shfl_up(x, o); if (lane >= o) x += y; }
        if (lane == 63) wsum[w] = x;
        __syncthreads();
        int add = carry;
        for (int k = 0; k < w; ++k) add += wsum[k];
        if (t < NB) boff[t] = add + x - v;   // exclusive
        __syncthreads();
        if (threadIdx.x == 0) carry += wsum[0] + wsum[1] + wsum[2] + wsum[3];
        __syncthreads();
    }
    if (threadIdx.x == 0) *offs_end = E;
}

__global__ void k_offs(const int* __restrict__ deg, const int* __restrict__ boff,
                       int* __restrict__ offs, int N) {
    __shared__ int wsum[4];
    int i = blockIdx.x * TPB + threadIdx.x;
    int v = (i < N) ? deg[i] : 0;
    int lane = threadIdx.x & 63, w = threadIdx.x >> 6;
    int x = v;
    for (int o = 1; o < 64; o <<= 1) { int y = __shfl_up(x, o); if (lane >= o) x += y; }
    if (lane == 63) wsum[w] = x;
    __syncthreads();
    int add = boff[blockIdx.x];
    for (int k = 0; k < w; ++k) add += wsum[k];
    if (i < N) offs[i] = add + x - v;
}

// ---- XCD-sliced scatter: slice = blockIdx&7 (round-robins onto one XCD);
// each slice writes only esrc positions for dst in its node range, so esrc
// lines stay in one L2 and write back once. Atomic-free (rank precomputed).
__global__ void k_scatter(const int* __restrict__ src, const int* __restrict__ dst,
                          const unsigned short* __restrict__ rank,
                          const int* __restrict__ offs,
                          unsigned short* __restrict__ esrc, int N, int E, int nchunk) {
    int slice = blockIdx.x & 7;
    int chunk = blockIdx.x >> 3;
    int lo = (int)((long long)N * slice >> 3);
    int hi = (int)((long long)N * (slice + 1) >> 3);
    for (int e = chunk * TPB + threadIdx.x; e < E; e += nchunk * TPB) {
        int d = dst[e];
        if (d >= lo && d < hi) {
            int pos = offs[d] + (int)rank[e];
            esrc[pos] = (unsigned short)src[e];
        }
    }
}

// ---- mean aggregate over bf16 h_hi; write c (bf16) interleaved into d_out ----
__global__ void k_agg(const unsigned short* __restrict__ h_hi, const int* __restrict__ offs,
                      const unsigned short* __restrict__ esrc, char* __restrict__ outb, int N) {
    int wid = (blockIdx.x * TPB + threadIdx.x) >> 6;
    int lane = threadIdx.x & 63;
    if (wid >= N) return;
    int beg = offs[wid], end = offs[wid + 1];
    const unsigned* h2 = (const unsigned*)h_hi;
    float ax0 = 0.f, ay0 = 0.f, ax1 = 0.f, ay1 = 0.f;
    int e = beg;
    for (; e + 3 < end; e += 4) {
        int s0 = esrc[e], s1 = esrc[e + 1], s2 = esrc[e + 2], s3 = esrc[e + 3];
        unsigned u0 = h2[(size_t)s0 * 64 + lane];
        unsigned u1 = h2[(size_t)s1 * 64 + lane];
        unsigned u2 = h2[(size_t)s2 * 64 + lane];
        unsigned u3 = h2[(size_t)s3 * 64 + lane];
        ax0 += __uint_as_float(u0 << 16) + __uint_as_float(u1 << 16);
        ay0 += __uint_as_float(u0 & 0xffff0000u) + __uint_as_float(u1 & 0xffff0000u);
        ax1 += __uint_as_float(u2 << 16) + __uint_as_float(u3 << 16);
        ay1 += __uint_as_float(u2 & 0xffff0000u) + __uint_as_float(u3 & 0xffff0000u);
    }
    for (; e < end; ++e) {
        unsigned u0 = h2[(size_t)esrc[e] * 64 + lane];
        ax0 += __uint_as_float(u0 << 16);
        ay0 += __uint_as_float(u0 & 0xffff0000u);
    }
    float ax = ax0 + ax1, ay = ay0 + ay1;
    float inv = 1.0f / fmaxf((float)(end - beg), 1.0f);
    unsigned pk = ((unsigned)f2bf(ay * inv) << 16) | (unsigned)f2bf(ax * inv);
    *(unsigned*)(outb + (size_t)wid * 512 + (size_t)lane * 4) = pk;
}

// ---- MFMA NodeApply: per wave 64 rows x 128 cols; A/B frags direct from cache ----
__launch_bounds__(TPB)
__global__ void k_apply(const unsigned short* __restrict__ h_hi,
                        const char* __restrict__ cl,        // d_out bytes: c + h_lo interleaved
                        const unsigned short* __restrict__ Wb,
                        const float* __restrict__ h,
                        const float* __restrict__ bia,
                        const float* __restrict__ snorm,
                        float* __restrict__ out, int N) {
    int lane = threadIdx.x & 63;
    int l15 = lane & 15, l4 = lane >> 4;
    int wave = threadIdx.x >> 6;
    int r0 = blockIdx.x * 256 + wave * 64;

    f32x4 acc[4][8] = {};

    #pragma unroll 2
    for (int kc = 0; kc < 8; ++kc) {
        bf16x8 Bf[8];
        #pragma unroll
        for (int n = 0; n < 8; ++n) {
            Bf[n] = *(const bf16x8*)((const char*)Wb +
                     ((size_t)(n * 16 + l15) * 512 + (size_t)kc * 64 + (size_t)l4 * 16));
        }
        #pragma unroll
        for (int rf = 0; rf < 4; ++rf) {
            int row = r0 + rf * 16 + l15;
            if (row > N - 1) row = N - 1;
            if (kc < 4) {
                bf16x8 ah = *(const bf16x8*)((const char*)h_hi +
                             ((size_t)row * 256 + (size_t)kc * 64 + (size_t)l4 * 16));
                bf16x8 al = *(const bf16x8*)(cl +
                             ((size_t)row * 512 + 256 + (size_t)kc * 64 + (size_t)l4 * 16));
                #pragma unroll
                for (int n = 0; n < 8; ++n) {
                    acc[rf][n] = __builtin_amdgcn_mfma_f32_16x16x32_bf16(ah, Bf[n], acc[rf][n], 0, 0, 0);
                    acc[rf][n] = __builtin_amdgcn_mfma_f32_16x16x32_bf16(al, Bf[n], acc[rf][n], 0, 0, 0);
                }
            } else {
                bf16x8 ac = *(const bf16x8*)(cl +
                             ((size_t)row * 512 + (size_t)(kc - 4) * 64 + (size_t)l4 * 16));
                #pragma unroll
                for (int n = 0; n < 8; ++n)
                    acc[rf][n] = __builtin_amdgcn_mfma_f32_16x16x32_bf16(ac, Bf[n], acc[rf][n], 0, 0, 0);
            }
        }
    }

    float bn[8];
    #pragma unroll
    for (int n = 0; n < 8; ++n) bn[n] = bia[n * 16 + l15];

    #pragma unroll
    for (int rf = 0; rf < 4; ++rf) {
        float sq[4] = {0.f, 0.f, 0.f, 0.f};
        #pragma unroll
        for (int n = 0; n < 8; ++n) {
            #pragma unroll
            for (int g = 0; g < 4; ++g) {
                acc[rf][n][g] += bn[n];
                sq[g] += acc[rf][n][g] * acc[rf][n][g];
            }
        }
        #pragma unroll
        for (int g = 0; g < 4; ++g) {
            sq[g] += __shfl_xor(sq[g], 1);
            sq[g] += __shfl_xor(sq[g], 2);
            sq[g] += __shfl_xor(sq[g], 4);
            sq[g] += __shfl_xor(sq[g], 8);
        }
        #pragma unroll
        for (int g = 0; g < 4; ++g) {
            int row = r0 + rf * 16 + l4 * 4 + g;
            if (row < N) {
                float invn = 1.0f / fmaxf(sqrtf(sq[g]), 1e-12f);
                float sn = snorm[row];
                #pragma unroll
                for (int n = 0; n < 8; ++n) {
                    int col = n * 16 + l15;
                    float v = fmaxf(acc[rf][n][g] * invn, 0.f) * sn + h[(size_t)row * 128 + col];
                    out[(size_t)row * 128 + col] = v;
                }
            }
        }
    }
}

extern "C" void kernel_launch(void* const* d_in, const int* in_sizes, int n_in,
                              void* d_out, int out_size, void* d_ws, size_t ws_size,
                              hipStream_t stream) {
    const float* h     = (const float*)d_in[0];
    const float* snorm = (const float*)d_in[1];
    const float* W     = (const float*)d_in[2];
    const float* b     = (const float*)d_in[3];
    const int*   src   = (const int*)d_in[4];
    const int*   dst   = (const int*)d_in[5];
    int N = in_sizes[1];
    int E = in_sizes[4];
    float* out = (float*)d_out;
    char* outb = (char*)d_out;

    char* ws = (char*)d_ws;
    size_t off = 0;
    auto alloc = [&](size_t bytes) {
        void* ptr = ws + off;
        off = (off + bytes + 255) & ~(size_t)255;
        return ptr;
    };
    int NB = (N + TPB - 1) / TPB;
    int* deg    = (int*)alloc((size_t)N * 4);
    int* offs   = (int*)alloc((size_t)(N + 1) * 4);
    int* bsum   = (int*)alloc((size_t)NB * 4);
    int* boff   = (int*)alloc((size_t)NB * 4);
    unsigned short* rank = (unsigned short*)alloc((size_t)E * 2);
    unsigned short* esrc = (unsigned short*)alloc((size_t)E * 2);
    unsigned short* h_hi = (unsigned short*)alloc((size_t)N * 128 * 2);
    unsigned short* Wb   = (unsigned short*)alloc((size_t)128 * 256 * 2);

    hipMemsetAsync(deg, 0, (size_t)N * 4, stream);

    int prep_items = N * 32 + 8192;
    int prep_grid = (prep_items > E ? prep_items : E);
    k_prep<<<(prep_grid + TPB - 1) / TPB, TPB, 0, stream>>>(h, W, dst, h_hi, outb, Wb,
                                                            deg, rank, N, E);

    k_bsum<<<NB, TPB, 0, stream>>>(deg, bsum, N);
    k_scanb<<<1, TPB, 0, stream>>>(bsum, boff, NB, offs + N, E);
    k_offs<<<NB, TPB, 0, stream>>>(deg, boff, offs, N);

    int nchunk = 512;
    k_scatter<<<8 * nchunk, TPB, 0, stream>>>(src, dst, rank, offs, esrc, N, E, nchunk);

    k_agg<<<((size_t)N * 64 + TPB - 1) / TPB, TPB, 0, stream>>>(h_hi, offs, esrc, outb, N);

    int nblk = (N + 255) / 256;
    k_apply<<<nblk, TPB, 0, stream>>>(h_hi, outb, Wb, h, b, snorm, out, N);
}